// Round 3
// baseline (249.545 us; speedup 1.0000x reference)
//
#include <hip/hip_runtime.h>
#include <hip/hip_bf16.h>

// GaussianModel covariance: cov = R(q_normalized) * diag(exp(2s)) * R^T, per point.
//
// Dtype model (settled R2): inputs FLOAT32 (R0: reading them as bf16 -> NaN),
// output FLOAT32 (R1: writing packed bf16 -> full-scale absmax 27383 ~= ref max,
// i.e. readback mismatched the stored format; the "bf16" in the test label is
// hard-coded text, not the output dtype).
//
// Memory-bound: 28 B read + 36 B write per point, N=4e6 -> 256 MB, ~41 us roofline.
// 2 points/thread: rot = 2x float4 (16B aligned), sca = 3x float2 (8B aligned),
// out = 9x float2 (byte offset 72*t, 8B aligned).

static __device__ __forceinline__ void cov_point(
    float w, float x, float y, float z,
    float s0, float s1, float s2, float c[9])
{
    float inv = rsqrtf(w * w + x * x + y * y + z * z);
    w *= inv; x *= inv; y *= inv; z *= inv;

    float r00 = 1.f - 2.f * (y * y + z * z);
    float r01 = 2.f * (x * y - w * z);
    float r02 = 2.f * (x * z + w * y);
    float r10 = 2.f * (x * y + w * z);
    float r11 = 1.f - 2.f * (x * x + z * z);
    float r12 = 2.f * (y * z - w * x);
    float r20 = 2.f * (x * z - w * y);
    float r21 = 2.f * (y * z + w * x);
    float r22 = 1.f - 2.f * (x * x + y * y);

    // cov[i][j] = sum_k R[i][k] * R[j][k] * exp(2*s_k)   (symmetric)
    float t0 = __expf(2.f * s0);
    float t1 = __expf(2.f * s1);
    float t2 = __expf(2.f * s2);

    c[0] = r00 * r00 * t0 + r01 * r01 * t1 + r02 * r02 * t2;
    c[1] = r00 * r10 * t0 + r01 * r11 * t1 + r02 * r12 * t2;
    c[2] = r00 * r20 * t0 + r01 * r21 * t1 + r02 * r22 * t2;
    c[3] = c[1];
    c[4] = r10 * r10 * t0 + r11 * r11 * t1 + r12 * r12 * t2;
    c[5] = r10 * r20 * t0 + r11 * r21 * t1 + r12 * r22 * t2;
    c[6] = c[2];
    c[7] = c[5];
    c[8] = r20 * r20 * t0 + r21 * r21 * t1 + r22 * r22 * t2;
}

__global__ __launch_bounds__(256) void gaussian_cov_kernel(
    const float4* __restrict__ rot,    // one float4 per point (w,x,y,z)
    const float2* __restrict__ sca,    // (N,3) f32 viewed as float2 pairs
    float2* __restrict__ out,          // (N,3,3) f32, 9 float2 per 2 points
    int npairs)
{
    int t = blockIdx.x * blockDim.x + threadIdx.x;
    if (t >= npairs) return;

    float4 q0 = rot[2 * t + 0];
    float4 q1 = rot[2 * t + 1];
    float2 f0 = sca[3 * t + 0];   // s0_0, s0_1
    float2 f1 = sca[3 * t + 1];   // s0_2, s1_0
    float2 f2 = sca[3 * t + 2];   // s1_1, s1_2

    float c0[9], c1[9];
    cov_point(q0.x, q0.y, q0.z, q0.w, f0.x, f0.y, f1.x, c0);
    cov_point(q1.x, q1.y, q1.z, q1.w, f1.y, f2.x, f2.y, c1);

    float2* o = out + (size_t)9 * (size_t)t;
    o[0] = make_float2(c0[0], c0[1]);
    o[1] = make_float2(c0[2], c0[3]);
    o[2] = make_float2(c0[4], c0[5]);
    o[3] = make_float2(c0[6], c0[7]);
    o[4] = make_float2(c0[8], c1[0]);
    o[5] = make_float2(c1[1], c1[2]);
    o[6] = make_float2(c1[3], c1[4]);
    o[7] = make_float2(c1[5], c1[6]);
    o[8] = make_float2(c1[7], c1[8]);
}

// Scalar tail for odd N (not hit at N=4e6; n is constant -> graph-capture safe).
__global__ void gaussian_cov_tail(
    const float* __restrict__ rot,
    const float* __restrict__ sca,
    float* __restrict__ out,
    int idx)
{
    float c[9];
    cov_point(rot[4 * idx + 0], rot[4 * idx + 1], rot[4 * idx + 2], rot[4 * idx + 3],
              sca[3 * idx + 0], sca[3 * idx + 1], sca[3 * idx + 2], c);
    for (int k = 0; k < 9; ++k)
        out[9 * idx + k] = c[k];
}

extern "C" void kernel_launch(void* const* d_in, const int* in_sizes, int n_in,
                              void* d_out, int out_size, void* d_ws, size_t ws_size,
                              hipStream_t stream) {
    const int n = in_sizes[0] / 4;   // number of points (4e6)
    const int npairs = n / 2;

    const float4* rot = (const float4*)d_in[0];
    const float2* sca = (const float2*)d_in[1];
    float2* out = (float2*)d_out;

    const int block = 256;
    const int grid = (npairs + block - 1) / block;
    gaussian_cov_kernel<<<grid, block, 0, stream>>>(rot, sca, out, npairs);

    if (n & 1) {
        gaussian_cov_tail<<<1, 1, 0, stream>>>(
            (const float*)d_in[0], (const float*)d_in[1],
            (float*)d_out, n - 1);
    }
}

// Round 4
// 229.534 us; speedup vs baseline: 1.0872x; 1.0872x over previous
//
#include <hip/hip_runtime.h>
#include <hip/hip_bf16.h>

// GaussianModel covariance: cov = R(q_normalized) * diag(exp(2s)) * R^T per point.
// Dtypes (settled R2, verified passing): f32 in, f32 out.
//
// R3 change: full LDS staging. R2 counters showed 2.1 TB/s (26% peak) with
// WRITE_SIZE ~= ideal -> request-amplification-bound, not volume-bound:
// 72 B-strided dwordx2 stores touched ~8 lines' worth of requests per line
// written. Now every global access is a coalesced float4 (64 lanes x 16 B
// contiguous); compute reads/writes go through an 18 KB LDS union buffer.
//
// Roofline: 28 B read + 36 B write per point, N=4e6 -> 256 MB, ~41 us @ 6.3 TB/s.

#define TPB 256
#define PPB 512   // points per block (2 per thread)

static __device__ __forceinline__ void cov_point(
    float w, float x, float y, float z,
    float s0, float s1, float s2, float c[9])
{
    float inv = rsqrtf(w * w + x * x + y * y + z * z);
    w *= inv; x *= inv; y *= inv; z *= inv;

    float r00 = 1.f - 2.f * (y * y + z * z);
    float r01 = 2.f * (x * y - w * z);
    float r02 = 2.f * (x * z + w * y);
    float r10 = 2.f * (x * y + w * z);
    float r11 = 1.f - 2.f * (x * x + z * z);
    float r12 = 2.f * (y * z - w * x);
    float r20 = 2.f * (x * z - w * y);
    float r21 = 2.f * (y * z + w * x);
    float r22 = 1.f - 2.f * (x * x + y * y);

    float t0 = __expf(2.f * s0);
    float t1 = __expf(2.f * s1);
    float t2 = __expf(2.f * s2);

    c[0] = r00 * r00 * t0 + r01 * r01 * t1 + r02 * r02 * t2;
    c[1] = r00 * r10 * t0 + r01 * r11 * t1 + r02 * r12 * t2;
    c[2] = r00 * r20 * t0 + r01 * r21 * t1 + r02 * r22 * t2;
    c[3] = c[1];
    c[4] = r10 * r10 * t0 + r11 * r11 * t1 + r12 * r12 * t2;
    c[5] = r10 * r20 * t0 + r11 * r21 * t1 + r12 * r22 * t2;
    c[6] = c[2];
    c[7] = c[5];
    c[8] = r20 * r20 * t0 + r21 * r21 * t1 + r22 * r22 * t2;
}

__global__ __launch_bounds__(TPB) void gaussian_cov_kernel(
    const float4* __restrict__ rot4,   // (N,4) f32 = N float4
    const float4* __restrict__ sca4,   // (N,3) f32 viewed as float4 (block-aligned)
    const float*  __restrict__ sca_f,  // scalar view for remainder
    float4* __restrict__ out4,         // (N,9) f32 viewed as float4 (block-aligned)
    float*  __restrict__ out_f,        // scalar view for remainder
    int n)
{
    // Union buffer: [stage-in: n_pt float4 rot (8 KB) + 3*n_pt floats sca (6 KB)]
    // then reused as [stage-out: 9*n_pt floats (18 KB)].
    __shared__ float lds[PPB * 9];     // 18432 B -> 8 blocks/CU, 32 waves/CU

    const int tid  = threadIdx.x;
    const int base = blockIdx.x * PPB;          // first point of this block
    const int n_pt = min(PPB, n - base);        // 512, or 256 in last block

    float4* lrot  = (float4*)lds;               // [0, 8192) B
    float*  lsca  = lds + 4 * PPB;              // [8192, 8192+3*PPB*4) B
    float4* lsca4 = (float4*)lsca;

    // ---- stage inputs, fully coalesced float4 ----
    for (int idx = tid; idx < n_pt; idx += TPB)
        lrot[idx] = rot4[base + idx];

    const int nsf = 3 * n_pt;                   // sca floats this block
    const int ns4 = nsf >> 2;
    const float4* gsca4 = sca4 + ((3 * base) >> 2);   // 3*base % 4 == 0 (base mult of 512)
    for (int idx = tid; idx < ns4; idx += TPB)
        lsca4[idx] = gsca4[idx];
    if (tid < (nsf & 3))                        // remainder floats (0 for this N)
        lsca[(ns4 << 2) + tid] = sca_f[3 * base + (ns4 << 2) + tid];

    __syncthreads();

    // ---- per-thread compute: 2 points from LDS into registers ----
    const int j0 = 2 * tid;
    const bool act0 = (j0 < n_pt);
    const bool act1 = (j0 + 1 < n_pt);

    float c0[9], c1[9];
    if (act0) {
        float4 q = lrot[j0];
        float s0 = lsca[6 * tid + 0], s1 = lsca[6 * tid + 1], s2 = lsca[6 * tid + 2];
        cov_point(q.x, q.y, q.z, q.w, s0, s1, s2, c0);
    }
    if (act1) {
        float4 q = lrot[j0 + 1];
        float s3 = lsca[6 * tid + 3], s4 = lsca[6 * tid + 4], s5 = lsca[6 * tid + 5];
        cov_point(q.x, q.y, q.z, q.w, s3, s4, s5, c1);
    }

    __syncthreads();   // all LDS input reads done before overwriting union buffer

    if (act0) {
        #pragma unroll
        for (int m = 0; m < 9; ++m) lds[18 * tid + m] = c0[m];
    }
    if (act1) {
        #pragma unroll
        for (int m = 0; m < 9; ++m) lds[18 * tid + 9 + m] = c1[m];
    }

    __syncthreads();

    // ---- stage output, fully coalesced float4 ----
    const int nof = 9 * n_pt;                   // out floats this block
    const int no4 = nof >> 2;
    float4* lout4 = (float4*)lds;
    float4* gout4 = out4 + ((9 * (size_t)base) >> 2);   // 9*base % 4 == 0 (base mult of 512)
    for (int idx = tid; idx < no4; idx += TPB)
        gout4[idx] = lout4[idx];
    if (tid < (nof & 3))                        // remainder floats (0 for this N)
        out_f[9 * (size_t)base + (no4 << 2) + tid] = lds[(no4 << 2) + tid];
}

extern "C" void kernel_launch(void* const* d_in, const int* in_sizes, int n_in,
                              void* d_out, int out_size, void* d_ws, size_t ws_size,
                              hipStream_t stream) {
    const int n = in_sizes[0] / 4;   // number of points (4e6)

    const float4* rot4 = (const float4*)d_in[0];
    const float4* sca4 = (const float4*)d_in[1];
    const float*  scaf = (const float*)d_in[1];
    float4* out4 = (float4*)d_out;
    float*  outf = (float*)d_out;

    const int grid = (n + PPB - 1) / PPB;
    gaussian_cov_kernel<<<grid, TPB, 0, stream>>>(rot4, sca4, scaf, out4, outf, n);
}

// Round 6
// 226.478 us; speedup vs baseline: 1.1019x; 1.0135x over previous
//
#include <hip/hip_runtime.h>
#include <hip/hip_bf16.h>

// GaussianModel covariance: cov = R(q_normalized) * diag(exp(2s)) * R^T per point.
// Dtypes (settled R2, verified): f32 in, f32 out.
//
// R5: same as R4, but nontemporal stores use a clang ext_vector_type — HIP's
// float4 is a class and __builtin_nontemporal_store rejects it (compile error).
//
// R4 changes vs R3 (kernel est. ~72 us, target ~50):
//  1. rot NOT staged through LDS — direct float4 loads (already lane-aligned).
//  2. Per-thread pair (tid, tid+256): sca LDS reads stride-3 (2-way alias, free),
//     out LDS writes stride-9 (free) instead of stride-18 (4-way, 1.58x).
//  3. Nontemporal float4 stores for the 144 MB output stream (don't evict the
//     112 MB resident inputs from L2/L3).
//
// Roofline: 28 B read + 36 B write per point, N=4e6 -> 256 MB, ~40 us @ 6.3 TB/s
// (harness's own fill kernels measure 6.7 TB/s write-only on this chip).

#define TPB 256
#define PPB 512   // points per block (2 per thread)

typedef float v4f __attribute__((ext_vector_type(4)));

static __device__ __forceinline__ void cov_point(
    float w, float x, float y, float z,
    float s0, float s1, float s2, float c[9])
{
    float inv = rsqrtf(w * w + x * x + y * y + z * z);
    w *= inv; x *= inv; y *= inv; z *= inv;

    float r00 = 1.f - 2.f * (y * y + z * z);
    float r01 = 2.f * (x * y - w * z);
    float r02 = 2.f * (x * z + w * y);
    float r10 = 2.f * (x * y + w * z);
    float r11 = 1.f - 2.f * (x * x + z * z);
    float r12 = 2.f * (y * z - w * x);
    float r20 = 2.f * (x * z - w * y);
    float r21 = 2.f * (y * z + w * x);
    float r22 = 1.f - 2.f * (x * x + y * y);

    float t0 = __expf(2.f * s0);
    float t1 = __expf(2.f * s1);
    float t2 = __expf(2.f * s2);

    c[0] = r00 * r00 * t0 + r01 * r01 * t1 + r02 * r02 * t2;
    c[1] = r00 * r10 * t0 + r01 * r11 * t1 + r02 * r12 * t2;
    c[2] = r00 * r20 * t0 + r01 * r21 * t1 + r02 * r22 * t2;
    c[3] = c[1];
    c[4] = r10 * r10 * t0 + r11 * r11 * t1 + r12 * r12 * t2;
    c[5] = r10 * r20 * t0 + r11 * r21 * t1 + r12 * r22 * t2;
    c[6] = c[2];
    c[7] = c[5];
    c[8] = r20 * r20 * t0 + r21 * r21 * t1 + r22 * r22 * t2;
}

__global__ __launch_bounds__(TPB) void gaussian_cov_kernel(
    const float4* __restrict__ rot4,   // (N,4) f32 = N float4, lane-aligned
    const float4* __restrict__ sca4,   // (N,3) f32 viewed as float4 (block-aligned)
    const float*  __restrict__ sca_f,  // scalar view for remainder
    v4f* __restrict__ out4,            // (N,9) f32 viewed as v4f (block-aligned)
    float* __restrict__ out_f,         // scalar view for remainder
    int n)
{
    // Union buffer: sca staging (6 KB) reused as out staging (18 KB).
    __shared__ float lds[PPB * 9];     // 18432 B

    const int tid  = threadIdx.x;
    const int base = blockIdx.x * PPB;
    const int n_pt = min(PPB, n - base);        // 512, or 256 in last block

    const bool act0 = (tid < n_pt);
    const bool act1 = (tid + TPB < n_pt);

    // ---- rot: direct coalesced float4 loads, no LDS ----
    float4 qa, qb;
    if (act0) qa = rot4[base + tid];
    if (act1) qb = rot4[base + TPB + tid];

    // ---- sca: stage via LDS, coalesced float4 ----
    float*  lsca  = lds;
    float4* lsca4 = (float4*)lds;
    const int nsf = 3 * n_pt;
    const int ns4 = nsf >> 2;
    const float4* gsca4 = sca4 + ((3 * base) >> 2);   // 3*base % 4 == 0
    for (int idx = tid; idx < ns4; idx += TPB)
        lsca4[idx] = gsca4[idx];
    if (tid < (nsf & 3))
        lsca[(ns4 << 2) + tid] = sca_f[3 * base + (ns4 << 2) + tid];

    __syncthreads();

    // ---- compute (sca reads: stride-3 floats -> 2-way bank alias, free) ----
    float c0[9], c1[9];
    if (act0)
        cov_point(qa.x, qa.y, qa.z, qa.w,
                  lsca[3 * tid + 0], lsca[3 * tid + 1], lsca[3 * tid + 2], c0);
    if (act1)
        cov_point(qb.x, qb.y, qb.z, qb.w,
                  lsca[3 * (TPB + tid) + 0], lsca[3 * (TPB + tid) + 1],
                  lsca[3 * (TPB + tid) + 2], c1);

    __syncthreads();   // sca reads done before union buffer is overwritten

    // ---- out to LDS (stride-9 floats -> 2-way alias, free) ----
    if (act0) {
        #pragma unroll
        for (int m = 0; m < 9; ++m) lds[9 * tid + m] = c0[m];
    }
    if (act1) {
        #pragma unroll
        for (int m = 0; m < 9; ++m) lds[9 * (TPB + tid) + m] = c1[m];
    }

    __syncthreads();

    // ---- copy out: coalesced nontemporal v4f ----
    const int nof = 9 * n_pt;
    const int no4 = nof >> 2;
    const v4f* lout4 = (const v4f*)lds;
    v4f* gout4 = out4 + ((9 * (size_t)base) >> 2);  // 9*base % 4 == 0
    for (int idx = tid; idx < no4; idx += TPB)
        __builtin_nontemporal_store(lout4[idx], &gout4[idx]);
    if (tid < (nof & 3))
        out_f[9 * (size_t)base + (no4 << 2) + tid] = lds[(no4 << 2) + tid];
}

extern "C" void kernel_launch(void* const* d_in, const int* in_sizes, int n_in,
                              void* d_out, int out_size, void* d_ws, size_t ws_size,
                              hipStream_t stream) {
    const int n = in_sizes[0] / 4;   // number of points (4e6)

    const float4* rot4 = (const float4*)d_in[0];
    const float4* sca4 = (const float4*)d_in[1];
    const float*  scaf = (const float*)d_in[1];
    v4f*   out4 = (v4f*)d_out;
    float* outf = (float*)d_out;

    const int grid = (n + PPB - 1) / PPB;
    gaussian_cov_kernel<<<grid, TPB, 0, stream>>>(rot4, sca4, scaf, out4, outf, n);
}